// Round 1
// 265.279 us; speedup vs baseline: 1.2065x; 1.2065x over previous
//
#include <hip/hip_runtime.h>
#include <math.h>

#define HID 50
#define TT  512
#define BT  16      // batch per block (= MFMA N)
#define NCW 13      // compute waves, one 16-row M-tile each; wave 13 = chore
#define NTH 896     // 14 waves
#define HS  72      // H plane row stride in shorts (144 B, 16B-aligned)
#define L2E 1.44269504088896f
#define K2C 2.88539008177793f   // 2*log2(e)

typedef __attribute__((ext_vector_type(8))) short bf16x8;
typedef __attribute__((ext_vector_type(4))) float f32x4;

__device__ __forceinline__ unsigned short bf16_rtne(float f) {
    unsigned u = __float_as_uint(f);
    u = (u + 0x7FFFu + ((u >> 16) & 1u)) >> 16;
    return (unsigned short)u;
}
__device__ __forceinline__ float bf16_f32(unsigned short s) {
    return __uint_as_float(((unsigned)s) << 16);
}

// R13: latency-bound recurrence → shorten the per-step serial span.
//  - 13 compute waves x 1 tile (was 7 x 2): halves per-wave serial work,
//    occupancy 23% -> 41%.
//  - y = W_out . h moved OFF the compute waves: chore wave does it with
//    2 MFMAs (A row0 = hi(W_out), row1 = lo(W_out); y = acc.x + acc.y).
//    Deletes 2 serial shfl_xor + ypart LDS from every compute wave.
//  - cell state carried pre-scaled: cs = 2*log2e*c, so Ec = exp2(cs)
//    directly (one fewer dependent mul); the two MFMAs use independent
//    accumulators + 4 adds (breaks the MFMA C-dependency chain).
// Math (A rows pre-scaled by log2e for i,f,o and 2*log2e for g):
//   Ei=2^-i', Ef=2^-f', Eg=2^g', Eo=2^-o'
//   cs = [cs*(1+Ei)(1+Eg) + K2*(Eg-1)*(1+Ef)] * rcp((1+Ef)(1+Ei)(1+Eg))
//   Ec = 2^cs;  h = (Ec-1) * rcp((1+Eo)(1+Ec))
// K-slots: 0..49 = s*W_hh | 50 = (s*Wih)_hi (x_hi) | 51 = (s*bias)_hi (1.0)
//          52 = (s*Wih)_hi (x_lo) | 53 = (s*bias)_lo (1.0) | 54 = (s*Wih)_lo (x_hi)
__global__ __launch_bounds__(NTH, 1) void lstm_mfma10_kernel(
    const float* __restrict__ x,      // [B, T]
    const float* __restrict__ W_ih,   // [200, 1]
    const float* __restrict__ W_hh,   // [200, 50]
    const float* __restrict__ b_ih,   // [200]
    const float* __restrict__ b_hh,   // [200]
    const float* __restrict__ W_out,  // [1, 50]
    const float* __restrict__ b_out,  // [1]
    float* __restrict__ out)          // [B, T]
{
    const int tid  = threadIdx.x;
    const int lane = tid & 63;
    const int wv   = tid >> 6;       // 0..13
    const int col  = lane & 15;      // A-m / B-n(batch) / D-col(batch)
    const int quad = lane >> 4;      // k-octet / D row-group

    __shared__ __align__(16) unsigned short Hh[2][BT][HS];

    // zero both H buffers (k-slots 55..63 + pads stay 0)
    for (int i = tid; i < 2 * BT * HS; i += NTH)
        (&Hh[0][0][0])[i] = 0;

    // persistent A fragments (single plane, PRE-SCALED rows)
    bf16x8 Ah[2];
    float cs = 0.f;                            // 2*log2e * c
    const int uo = wv * 4 + quad;              // output unit of this lane

    if (wv < NCW) {
        const int gh  = wv * 16 + col;          // g^ row
        const int u   = gh >> 2;
        const int ty  = gh & 3;
        const bool vl = (u < HID);
        const int og  = ty * HID + u;           // original gate row
        const float sc = (ty == 2) ? K2C : L2E;
        #pragma unroll
        for (int kk = 0; kk < 2; ++kk) {
            #pragma unroll
            for (int j = 0; j < 8; ++j) {
                const int k = kk * 32 + quad * 8 + j;
                float v = 0.f;
                if (vl) {
                    if (k < HID)      v = sc * W_hh[og * HID + k];
                    else if (k == 50) v = sc * W_ih[og];
                    else if (k == 51) v = sc * (b_ih[og] + b_hh[og]);
                    else if (k == 52) v = sc * W_ih[og];
                    else if (k == 53) {
                        const float sb = sc * (b_ih[og] + b_hh[og]);
                        v = sb - bf16_f32(bf16_rtne(sb));
                    } else if (k == 54) {
                        const float sw = sc * W_ih[og];
                        v = sw - bf16_f32(bf16_rtne(sw));
                    }
                }
                Ah[kk][j] = (short)bf16_rtne(v);
            }
        }
    } else {
        // chore wave: A row0 = hi(W_out), row1 = W_out - hi(W_out)
        #pragma unroll
        for (int kk = 0; kk < 2; ++kk) {
            #pragma unroll
            for (int j = 0; j < 8; ++j) {
                const int k = kk * 32 + quad * 8 + j;
                const float v = (k < HID) ? W_out[k] : 0.f;
                const unsigned short hi = bf16_rtne(v);
                short val = 0;
                if (col == 0)      val = (short)hi;
                else if (col == 1) val = (short)bf16_rtne(v - bf16_f32(hi));
                Ah[kk][j] = val;
            }
        }
    }
    const float bo = b_out[0];
    float* yout = out + (size_t)blockIdx.x * BT * TT;

    // chore-wave x pipeline state (lanes 16..31 own batch b = lane-16)
    const int xb = (lane >= 16) ? (lane - 16) : 0;
    const float* xrow = x + (size_t)(blockIdx.x * BT + xb) * TT;
    float xa = 0.f;
    if (wv == NCW && lane >= 16 && lane < 32)
        xa = xrow[1];                            // x[b][1] for step t=0's write

    __syncthreads();    // zeroed H visible

    // buffer-0 slots for t=0: x_0 hi/lo + bias-1.0 markers (packed b32 writes)
    if (tid < BT) {
        const float x0 = x[(size_t)(blockIdx.x * BT + tid) * TT];
        const unsigned short hx = bf16_rtne(x0);
        const unsigned short lx = bf16_rtne(x0 - bf16_f32(hx));
        unsigned* row32 = (unsigned*)&Hh[0][tid][0];
        row32[25] = (unsigned)hx | (0x3F80u << 16);   // k=50,51
        row32[26] = (unsigned)lx | (0x3F80u << 16);   // k=52,53
        Hh[0][tid][54] = hx;                          // k=54
    }
    __syncthreads();

    for (int t = 0; t < TT; ++t) {
        const int p = t & 1;        // read buffer; write 1-p

        if (wv < NCW) {
            // ---- compute wave: one tile ----
            const unsigned short* hrow = &Hh[p][col][0];
            const bf16x8 B0 = *(const bf16x8*)&hrow[quad * 8];
            const bf16x8 B1 = *(const bf16x8*)&hrow[32 + quad * 8];

            const f32x4 z = {0.f, 0.f, 0.f, 0.f};
            f32x4 a0 = __builtin_amdgcn_mfma_f32_16x16x32_bf16(Ah[0], B0, z, 0, 0, 0);
            f32x4 a1 = __builtin_amdgcn_mfma_f32_16x16x32_bf16(Ah[1], B1, z, 0, 0, 0);
            const float gi = a0.x + a1.x;
            const float gf = a0.y + a1.y;
            const float gg = a0.z + a1.z;
            const float go = a0.w + a1.w;

            const float Ei = __builtin_amdgcn_exp2f(-gi);
            const float Ef = __builtin_amdgcn_exp2f(-gf);
            const float Eg = __builtin_amdgcn_exp2f(gg);
            const float Eo = __builtin_amdgcn_exp2f(-go);
            const float DIG = (1.f + Ei) * (1.f + Eg);
            const float DF  = 1.f + Ef;
            const float t1  = fmaf(K2C, Eg, -K2C);          // K2*(Eg-1)
            const float num = fmaf(cs, DIG, t1 * DF);
            cs = num * __builtin_amdgcn_rcpf(DF * DIG);     // 2*log2e*c_t
            const float Ec = __builtin_amdgcn_exp2f(cs);
            const float h  = (Ec - 1.f) *
                             __builtin_amdgcn_rcpf((1.f + Eo) * (1.f + Ec));
            if (uo < HID)
                Hh[1 - p][col][uo] = bf16_rtne(h);
        } else {
            // ---- chore wave: x slots, y via MFMA, y store ----
            const unsigned short* hrow = &Hh[p][col][0];
            const bf16x8 B0 = *(const bf16x8*)&hrow[quad * 8];
            const bf16x8 B1 = *(const bf16x8*)&hrow[32 + quad * 8];

            if (lane >= 16 && lane < 32) {
                // x_{t+1} slots from register xa; prefetch x[b][t+2]
                const int b = lane - 16;
                const unsigned short hx = bf16_rtne(xa);
                const unsigned short lx = bf16_rtne(xa - bf16_f32(hx));
                unsigned* row32 = (unsigned*)&Hh[1 - p][b][0];
                row32[25] = (unsigned)hx | (0x3F80u << 16);   // k=50,51
                row32[26] = (unsigned)lx | (0x3F80u << 16);   // k=52,53
                Hh[1 - p][b][54] = hx;                        // k=54
                xa = xrow[(t + 2 < TT) ? t + 2 : TT - 1];
            }

            const f32x4 z = {0.f, 0.f, 0.f, 0.f};
            f32x4 a0 = __builtin_amdgcn_mfma_f32_16x16x32_bf16(Ah[0], B0, z, 0, 0, 0);
            a0 = __builtin_amdgcn_mfma_f32_16x16x32_bf16(Ah[1], B1, a0, 0, 0, 0);
            // D row0 (hi) + row1 (lo) live in acc.x/acc.y of lanes 0..15
            if (lane < 16 && t > 0)
                yout[(size_t)lane * TT + (t - 1)] = a0.x + a0.y + bo;
        }

        __syncthreads();    // the ONE barrier
    }

    // epilogue: y_{TT-1} from Hh[0] (h_{511})
    if (wv == NCW) {
        const unsigned short* hrow = &Hh[0][col][0];
        const bf16x8 B0 = *(const bf16x8*)&hrow[quad * 8];
        const bf16x8 B1 = *(const bf16x8*)&hrow[32 + quad * 8];
        const f32x4 z = {0.f, 0.f, 0.f, 0.f};
        f32x4 a0 = __builtin_amdgcn_mfma_f32_16x16x32_bf16(Ah[0], B0, z, 0, 0, 0);
        a0 = __builtin_amdgcn_mfma_f32_16x16x32_bf16(Ah[1], B1, a0, 0, 0, 0);
        if (lane < 16)
            yout[(size_t)lane * TT + (TT - 1)] = a0.x + a0.y + bo;
    }
}

extern "C" void kernel_launch(void* const* d_in, const int* in_sizes, int n_in,
                              void* d_out, int out_size, void* d_ws, size_t ws_size,
                              hipStream_t stream) {
    const float* x     = (const float*)d_in[0];
    const float* W_ih  = (const float*)d_in[1];
    const float* W_hh  = (const float*)d_in[2];
    const float* b_ih  = (const float*)d_in[3];
    const float* b_hh  = (const float*)d_in[4];
    const float* W_out = (const float*)d_in[5];
    const float* b_out = (const float*)d_in[6];
    float* out = (float*)d_out;

    const int B = in_sizes[0] / TT;          // 4096
    lstm_mfma10_kernel<<<B / BT, NTH, 0, stream>>>(x, W_ih, W_hh, b_ih, b_hh,
                                                   W_out, b_out, out);
}